// Round 11
// baseline (290.380 us; speedup 1.0000x reference)
//
#include <hip/hip_runtime.h>
#include <stdint.h>

#define WB 8
#define WC 32
#define WU 32
#define WK 5
#define WN 256
#define NN 65536     // 256*256
#define KC 160       // WK*WC
#define KQ 1280      // WK*WN

typedef __attribute__((ext_vector_type(8))) short bf8;     // 8 x bf16
typedef __attribute__((ext_vector_type(8))) unsigned short us8;
typedef __attribute__((ext_vector_type(4))) float f4;

__device__ __forceinline__ unsigned short f2b(float f) {
    union { float f; uint32_t u; } v; v.f = f;
    uint32_t u = v.u;
    return (unsigned short)((u + 0x7FFFu + ((u >> 16) & 1u)) >> 16);  // RNE
}

// async global->LDS, 16B per lane; lds base must be wave-uniform (m97 pattern)
__device__ __forceinline__ void gload16(const unsigned short* g, unsigned short* l) {
    __builtin_amdgcn_global_load_lds(
        (const __attribute__((address_space(1))) unsigned int*)g,
        (__attribute__((address_space(3))) unsigned int*)l, 16, 0, 0);
}

// ---------------------------------------------------------------------------
// P0: repacks (bf16): c1T[k][m][p], c2T[n][l*256+q], Wt[(l,u)][(k,i)]
// ---------------------------------------------------------------------------
__global__ void prep_small(const float* __restrict__ cheb1,
                           const float* __restrict__ cheb2,
                           const float* __restrict__ coefs,
                           unsigned short* __restrict__ c1T,
                           unsigned short* __restrict__ c2T,
                           unsigned short* __restrict__ Wt) {
    int idx = blockIdx.x * 256 + threadIdx.x;
    if (idx < WK * NN) {            // c1T[k][m][p] = cheb1[k][p][m]
        int k = idx / NN, r = idx % NN, m = r / WN, p = r % WN;
        c1T[idx] = f2b(cheb1[(k * WN + p) * WN + m]);
    }
    if (idx < WN * KQ) {            // c2T[n][lq] = cheb2[lq][n]
        int n = idx / KQ, r = idx % KQ;
        c2T[idx] = f2b(cheb2[r * WN + n]);
    }
    if (idx < KC * KC) {            // Wt[l*32+u][k*32+i] = coefs[k][l][i][u]
        int lu = idx / KC, ki = idx % KC;
        int l = lu >> 5, u = lu & 31, k = ki >> 5, i = ki & 31;
        Wt[idx] = f2b(coefs[((k * WK + l) * WC + i) * WU + u]);
    }
}

// ---------------------------------------------------------------------------
// P1: xT[b][i][q][p] (bf16) = x[b][i][p][q]
// ---------------------------------------------------------------------------
__global__ void prep_x(const float* __restrict__ x, unsigned short* __restrict__ xT) {
    __shared__ unsigned short tile[64][72];
    int bi = blockIdx.z;
    int p0 = blockIdx.y * 64, q0 = blockIdx.x * 64;
    const float* src = x + (size_t)bi * NN;
    unsigned short* dst = xT + (size_t)bi * NN;
    int t = threadIdx.x;
    int c4 = (t & 15) * 4, r0 = t >> 4;
    for (int it = 0; it < 4; ++it) {
        int r = r0 + it * 16;
        float4 v = *reinterpret_cast<const float4*>(&src[(size_t)(p0 + r) * WN + q0 + c4]);
        tile[r][c4 + 0] = f2b(v.x); tile[r][c4 + 1] = f2b(v.y);
        tile[r][c4 + 2] = f2b(v.z); tile[r][c4 + 3] = f2b(v.w);
    }
    __syncthreads();
    for (int it = 0; it < 4; ++it) {
        int q = r0 + it * 16;
        ushort4 o;
        o.x = tile[c4 + 0][q]; o.y = tile[c4 + 1][q];
        o.z = tile[c4 + 2][q]; o.w = tile[c4 + 3][q];
        *reinterpret_cast<ushort4*>(&dst[(size_t)(q0 + q) * WN + p0 + c4]) = o;
    }
}

// ---------------------------------------------------------------------------
// G1: per (b,i): a[ki][m][q] = sum_p c1T[(k,m)][p] * xT[b,i][q][p]
//     r10 pipeline (A dbuf, vmcnt(2), XCD-grouped swizzle) unchanged;
//     epilogue writes a in g2p-contiguous layout a[pixg][ki][pixlo]
//     (pix = m*256+q, pixg = pix>>4, pixlo = pix&15 = lr; 32B coalesced).
// ---------------------------------------------------------------------------
__global__ __launch_bounds__(512, 4) void g1(const unsigned short* __restrict__ c1T,
                                             const unsigned short* __restrict__ xT,
                                             unsigned short* __restrict__ a, int b_base) {
    __shared__ unsigned short As[2][128 * 64];   // 32 KB
    __shared__ unsigned short Bs[256 * 64];      // 32 KB
    // XCD-grouped decode: nblk = 320*cur, gpx = groups per XCD = 4*cur
    int p = blockIdx.x;
    int gpx = gridDim.x / 80;
    int xcd = p & 7, j = p >> 3;
    int grp = xcd * gpx + j / 10;           // bi group in [0, cur*32)
    int member = j % 10;                    // row-tile 0..9
    int bl = grp >> 5, i = grp & 31;
    int row0 = member * 128;                // (k,m) row base
    int b = b_base + bl;
    const unsigned short* Asrc = c1T;                              // pitch 256
    const unsigned short* Bsrc = xT + (size_t)(b * WC + i) * NN;   // [q][p], pitch 256
    unsigned short* Out = a + (size_t)bl * KC * NN;

    int t = threadIdx.x;
    int w = t >> 6, l = t & 63;
    int wm = (w >> 2) * 64, wn = (w & 3) * 64;
    int lr = l & 15, hi = l >> 4;
    int srow = l >> 3;                       // 0..7 within 8-row chunk
    int scol = ((l & 7) ^ srow) * 8;         // pre-swizzled source col (elems)

    f4 acc[4][4];
    for (int mf = 0; mf < 4; ++mf) for (int nf = 0; nf < 4; ++nf) acc[mf][nf] = (f4)(0.0f);

#define G1_STAGE_A(buf, step) do { \
    int p0_ = (step) * 64; \
    for (int it = 0; it < 2; ++it) { \
        int chunk = it * 8 + w; int row = chunk * 8 + srow; \
        gload16(&Asrc[(size_t)(row0 + row) * 256 + p0_ + scol], &As[buf][chunk * 512]); } \
} while (0)
#define G1_STAGE_B(step) do { \
    int p0_ = (step) * 64; \
    for (int it = 0; it < 4; ++it) { \
        int chunk = it * 8 + w; int row = chunk * 8 + srow; \
        gload16(&Bsrc[(size_t)row * 256 + p0_ + scol], &Bs[chunk * 512]); } \
} while (0)

    G1_STAGE_A(0, 0);                        // prologue: A(0) in flight
    for (int step = 0; step < 4; ++step) {
        int cur = step & 1;
        G1_STAGE_B(step);                    // B(t): 4 loads
        if (step < 3) {
            G1_STAGE_A(cur ^ 1, step + 1);   // A(t+1): 2 loads
            // outstanding: A(t)2 + B(t)4 + A(t+1)2 = 8 -> keep newest 2
            asm volatile("s_waitcnt vmcnt(2)" ::: "memory");
        } else {
            asm volatile("s_waitcnt vmcnt(0)" ::: "memory");
        }
        __builtin_amdgcn_s_barrier();        // tile t visible to all waves
        asm volatile("" ::: "memory");
        for (int kk = 0; kk < 2; ++kk) {
            bf8 af[4], bfr[4];
            for (int mf = 0; mf < 4; ++mf) {
                int r = wm + mf * 16 + lr;
                af[mf] = *(const bf8*)&As[cur][r * 64 + (((kk * 4 + hi) ^ (r & 7)) * 8)];
            }
            for (int nf = 0; nf < 4; ++nf) {
                int rb = wn + nf * 16 + lr;
                bfr[nf] = *(const bf8*)&Bs[rb * 64 + (((kk * 4 + hi) ^ (rb & 7)) * 8)];
            }
            for (int mf = 0; mf < 4; ++mf)
                for (int nf = 0; nf < 4; ++nf)
                    acc[mf][nf] = __builtin_amdgcn_mfma_f32_16x16x32_bf16(af[mf], bfr[nf], acc[mf][nf], 0, 0, 0);
        }
        asm volatile("" ::: "memory");
        __builtin_amdgcn_s_barrier();        // done reading Bs / As[cur]
    }
#undef G1_STAGE_A
#undef G1_STAGE_B
    for (int mf = 0; mf < 4; ++mf)
        for (int nf = 0; nf < 4; ++nf) {
            int qv = wn + nf * 16;                         // q = qv + lr
            for (int j2 = 0; j2 < 4; ++j2) {
                int grow = row0 + wm + mf * 16 + hi * 4 + j2;   // (k,m)
                int k = grow >> 8, m = grow & 255;
                int pixg = m * 16 + (qv >> 4);
                Out[(size_t)pixg * 2560 + (k * 32 + i) * 16 + lr] = f2b(acc[mf][nf][j2]);
            }
        }
}

// ---------------------------------------------------------------------------
// G2P: c[(l,u)][pix] = Wt[160x160] @ a  — per batch M=160, N=65536, K=160.
//     a is [pixg][ki][pixlo]: block's 8 pixg = CONTIGUOUS 40KB -> pure
//     gload16 staging (no transpose, no ds_writes; 40KB LDS = 4 blocks/CU).
//     B-frags: 8x ds_read_u16 at 32B stride (4-way bank alias, ~free-ish).
//     Wt A-frags from global (L2-hot) and epilogue unchanged (PASS-proven).
// ---------------------------------------------------------------------------
__global__ __launch_bounds__(512, 4) void g2p(const unsigned short* __restrict__ Wt,
                                              const unsigned short* __restrict__ a,
                                              unsigned short* __restrict__ c) {
    __shared__ unsigned short Bt[20480];     // 8 pixg x 160 ki x 16 pixlo
    int bl = blockIdx.y;
    int n0 = blockIdx.x * 128;
    const unsigned short* asrc = a + (size_t)bl * KC * NN + (size_t)(n0 >> 4) * 2560;
    unsigned short* Out = c + (size_t)bl * KC * NN;
    int t = threadIdx.x;
    int w = t >> 6, l = t & 63;

    for (int s = 0; s < 5; ++s)
        gload16(&asrc[(size_t)(s * 512 + t) * 8], &Bt[(s * 512 + w * 64) * 8]);
    __syncthreads();

    int mh = w >> 2, nq = w & 3;
    int lr = l & 15, hi = l >> 4;
    f4 acc[5][2];
    for (int mf = 0; mf < 5; ++mf) { acc[mf][0] = (f4)(0.0f); acc[mf][1] = (f4)(0.0f); }

    for (int kk = 0; kk < 5; ++kk) {
        int k0 = kk * 32 + hi * 8;
        bf8 bfr[2];
        #pragma unroll
        for (int nf = 0; nf < 2; ++nf) {
            int base = (nq * 2 + nf) * 2560 + lr;   // pixg_local*2560 + pixlo
            bf8 v;
            #pragma unroll
            for (int e = 0; e < 8; ++e)
                v[e] = (short)Bt[base + (k0 + e) * 16];
            bfr[nf] = v;
        }
        #pragma unroll
        for (int mf = 0; mf < 5; ++mf) {
            int row = mh * 80 + mf * 16 + lr;
            bf8 afr = *(const bf8*)&Wt[(size_t)row * KC + k0];
            acc[mf][0] = __builtin_amdgcn_mfma_f32_16x16x32_bf16(afr, bfr[0], acc[mf][0], 0, 0, 0);
            acc[mf][1] = __builtin_amdgcn_mfma_f32_16x16x32_bf16(afr, bfr[1], acc[mf][1], 0, 0, 0);
        }
    }
    for (int mf = 0; mf < 5; ++mf)
        for (int nf = 0; nf < 2; ++nf)
            for (int j = 0; j < 4; ++j) {
                int row = mh * 80 + mf * 16 + hi * 4 + j;       // (l,u)
                int col = n0 + (nq * 2 + nf) * 16 + lr;         // pix
                Out[(size_t)row * NN + col] = f2b(acc[mf][nf][j]);
            }
}

// ---------------------------------------------------------------------------
// G3: out[b][u][m][n] = sum_{l,q} c[(l*32+u)][(m,q)] * c2T[n][(l,q)]
//     (r9 PASS version: A dbuf 2x16KB, B 32KB, vmcnt(2), ~62us)
// ---------------------------------------------------------------------------
__global__ __launch_bounds__(512, 4) void g3(const unsigned short* __restrict__ c,
                                             const unsigned short* __restrict__ c2T,
                                             float* __restrict__ out, int b_base) {
    __shared__ unsigned short As[2][128 * 64];     // 32 KB
    __shared__ unsigned short Bs[256 * 64];        // 32 KB
    int bl = blockIdx.y;
    int b = b_base + bl;
    int R0 = blockIdx.x * 128;             // (u,m); u fixed per block
    int u = R0 >> 8, m0 = R0 & 255;
    const unsigned short* Csrc = c + (size_t)bl * KC * NN;

    int t = threadIdx.x;
    int w = t >> 6, l = t & 63;
    int wm = (w >> 2) * 64, wn = (w & 3) * 64;
    int lr = l & 15, hi = l >> 4;
    int srow = l >> 3;
    int scol = ((l & 7) ^ srow) * 8;

    f4 acc[4][4];
    for (int mf = 0; mf < 4; ++mf) for (int nf = 0; nf < 4; ++nf) acc[mf][nf] = (f4)(0.0f);

#define G3_STAGE_A(buf, step) do { \
    int lq_ = (step) >> 2, q0_ = ((step) & 3) * 64; \
    const unsigned short* Arow0 = Csrc + (size_t)(lq_ * 32 + u) * NN + (size_t)m0 * 256 + q0_; \
    for (int it = 0; it < 2; ++it) { \
        int chunk = it * 8 + w; int row = chunk * 8 + srow; \
        gload16(&Arow0[(size_t)row * 256 + scol], &As[buf][chunk * 512]); } \
} while (0)
#define G3_STAGE_B(step) do { \
    const unsigned short* Brow0 = c2T + (step) * 64; \
    for (int it = 0; it < 4; ++it) { \
        int chunk = it * 8 + w; int row = chunk * 8 + srow; \
        gload16(&Brow0[(size_t)row * KQ + scol], &Bs[chunk * 512]); } \
} while (0)

    G3_STAGE_A(0, 0);                        // prologue: A(0) in flight
    for (int step = 0; step < 20; ++step) {
        int cur = step & 1;
        G3_STAGE_B(step);                    // B(t): 4 loads, L2-hot
        if (step < 19) {
            G3_STAGE_A(cur ^ 1, step + 1);   // A(t+1): 2 loads, one step early
            asm volatile("s_waitcnt vmcnt(2)" ::: "memory");
        } else {
            asm volatile("s_waitcnt vmcnt(0)" ::: "memory");
        }
        __builtin_amdgcn_s_barrier();        // tile t visible to all waves
        asm volatile("" ::: "memory");
        for (int kk = 0; kk < 2; ++kk) {
            bf8 af[4], bfr[4];
            for (int mf = 0; mf < 4; ++mf) {
                int r = wm + mf * 16 + lr;
                af[mf] = *(const bf8*)&As[cur][r * 64 + (((kk * 4 + hi) ^ (r & 7)) * 8)];
            }
            for (int nf = 0; nf < 4; ++nf) {
                int rb = wn + nf * 16 + lr;
                bfr[nf] = *(const bf8*)&Bs[rb * 64 + (((kk * 4 + hi) ^ (rb & 7)) * 8)];
            }
            for (int mf = 0; mf < 4; ++mf)
                for (int nf = 0; nf < 4; ++nf)
                    acc[mf][nf] = __builtin_amdgcn_mfma_f32_16x16x32_bf16(af[mf], bfr[nf], acc[mf][nf], 0, 0, 0);
        }
        asm volatile("" ::: "memory");
        __builtin_amdgcn_s_barrier();        // done reading Bs / As[cur]
    }
#undef G3_STAGE_A
#undef G3_STAGE_B
    for (int mf = 0; mf < 4; ++mf)
        for (int nf = 0; nf < 4; ++nf)
            for (int j = 0; j < 4; ++j) {
                int m = m0 + wm + mf * 16 + hi * 4 + j;
                int n = wn + nf * 16 + lr;
                out[((size_t)(b * WU + u) * WN + m) * WN + n] = acc[mf][nf][j];
            }
}

// ---------------------------------------------------------------------------
extern "C" void kernel_launch(void* const* d_in, const int* in_sizes, int n_in,
                              void* d_out, int out_size, void* d_ws, size_t ws_size,
                              hipStream_t stream) {
    const float* x     = (const float*)d_in[0];
    const float* cheb1 = (const float*)d_in[1];
    const float* cheb2 = (const float*)d_in[2];
    const float* coefs = (const float*)d_in[3];
    float* out = (float*)d_out;
    unsigned short* ws = (unsigned short*)d_ws;

    size_t off = 0;
    unsigned short* xT  = ws + off; off += (size_t)WB * WC * NN;
    unsigned short* c1T = ws + off; off += (size_t)WK * NN;
    unsigned short* c2T = ws + off; off += (size_t)WN * KQ;
    unsigned short* Wt  = ws + off; off += (size_t)KC * KC;
    size_t fixed_elems = off;
    size_t a1 = (size_t)KC * NN;                 // one batch of a or c (elems)

    prep_small<<<1280, 256, 0, stream>>>(cheb1, cheb2, coefs, c1T, c2T, Wt);
    prep_x<<<dim3(4, 4, WB * WC), 256, 0, stream>>>(x, xT);

    size_t avail = ws_size / 2;
    size_t rem = avail > fixed_elems ? avail - fixed_elems : 0;

    if (rem >= 9 * a1) {
        // full-c path: chunk a by nb batches, single g3 over all 8
        int nb = (int)((rem - 8 * a1) / a1);
        if (nb < 1) nb = 1;
        if (nb > WB) nb = WB;
        unsigned short* a_ = ws + fixed_elems;
        unsigned short* c_ = a_ + (size_t)nb * a1;
        for (int b0 = 0; b0 < WB; b0 += nb) {
            int cur = (WB - b0 < nb) ? (WB - b0) : nb;
            g1<<<dim3(cur * 320), 512, 0, stream>>>(c1T, xT, a_, b0);
            g2p<<<dim3(512, cur), 512, 0, stream>>>(Wt, a_, c_ + (size_t)b0 * a1);
        }
        g3<<<dim3(64, WB), 512, 0, stream>>>(c_, c2T, out, 0);
    } else {
        // chunked fallback
        size_t per_b = 2 * a1;
        int nb = (int)(rem / per_b);
        if (nb < 1) nb = 1;
        if (nb > WB) nb = WB;
        unsigned short* a_ = ws + fixed_elems;
        unsigned short* c_ = a_ + (size_t)nb * a1;
        for (int b0 = 0; b0 < WB; b0 += nb) {
            int cur = (WB - b0 < nb) ? (WB - b0) : nb;
            g1<<<dim3(cur * 320), 512, 0, stream>>>(c1T, xT, a_, b0);
            g2p<<<dim3(512, cur), 512, 0, stream>>>(Wt, a_, c_);
            g3<<<dim3(64, cur), 512, 0, stream>>>(c_, c2T, out, b0);
        }
    }
}

// Round 12
// 262.825 us; speedup vs baseline: 1.1048x; 1.1048x over previous
//
#include <hip/hip_runtime.h>
#include <stdint.h>

#define WB 8
#define WC 32
#define WU 32
#define WK 5
#define WN 256
#define NN 65536     // 256*256
#define KC 160       // WK*WC
#define KQ 1280      // WK*WN

typedef __attribute__((ext_vector_type(8))) short bf8;     // 8 x bf16
typedef __attribute__((ext_vector_type(8))) unsigned short us8;
typedef __attribute__((ext_vector_type(4))) float f4;

__device__ __forceinline__ unsigned short f2b(float f) {
    union { float f; uint32_t u; } v; v.f = f;
    uint32_t u = v.u;
    return (unsigned short)((u + 0x7FFFu + ((u >> 16) & 1u)) >> 16);  // RNE
}

// async global->LDS, 16B per lane; lds base must be wave-uniform (m97 pattern)
__device__ __forceinline__ void gload16(const unsigned short* g, unsigned short* l) {
    __builtin_amdgcn_global_load_lds(
        (const __attribute__((address_space(1))) unsigned int*)g,
        (__attribute__((address_space(3))) unsigned int*)l, 16, 0, 0);
}

// ---------------------------------------------------------------------------
// P0: repacks (bf16): c1T[k][m][p], c2T[n][l*256+q],
//     WtP = Wt pre-packed in MFMA A-fragment order:
//     WtP[(((mh*5+kk)*5+mf)*64 + lane)*8 + e] = Wt[mh*80+mf*16+(lane&15)]
//                                                 [kk*32+(lane>>4)*8+e]
//     where Wt[l*32+u][k*32+i] = coefs[k][l][i][u].
// ---------------------------------------------------------------------------
__global__ void prep_small(const float* __restrict__ cheb1,
                           const float* __restrict__ cheb2,
                           const float* __restrict__ coefs,
                           unsigned short* __restrict__ c1T,
                           unsigned short* __restrict__ c2T,
                           unsigned short* __restrict__ WtP) {
    int idx = blockIdx.x * 256 + threadIdx.x;
    if (idx < WK * NN) {            // c1T[k][m][p] = cheb1[k][p][m]
        int k = idx / NN, r = idx % NN, m = r / WN, p = r % WN;
        c1T[idx] = f2b(cheb1[(k * WN + p) * WN + m]);
    }
    if (idx < WN * KQ) {            // c2T[n][lq] = cheb2[lq][n]
        int n = idx / KQ, r = idx % KQ;
        c2T[idx] = f2b(cheb2[r * WN + n]);
    }
    if (idx < KC * KC) {            // fragment-packed Wt
        int e = idx & 7, lane = (idx >> 3) & 63, r = idx >> 9;   // r < 50
        int mf = r % 5, kk = (r / 5) % 5, mh = r / 25;
        int lu = mh * 80 + mf * 16 + (lane & 15);    // (l,u) row
        int ki = kk * 32 + (lane >> 4) * 8 + e;      // (k,i) col
        int l = lu >> 5, u = lu & 31, k = ki >> 5, i = ki & 31;
        WtP[idx] = f2b(coefs[((k * WK + l) * WC + i) * WU + u]);
    }
}

// ---------------------------------------------------------------------------
// P1: xT[b][i][q][p] (bf16) = x[b][i][p][q]
// ---------------------------------------------------------------------------
__global__ void prep_x(const float* __restrict__ x, unsigned short* __restrict__ xT) {
    __shared__ unsigned short tile[64][72];
    int bi = blockIdx.z;
    int p0 = blockIdx.y * 64, q0 = blockIdx.x * 64;
    const float* src = x + (size_t)bi * NN;
    unsigned short* dst = xT + (size_t)bi * NN;
    int t = threadIdx.x;
    int c4 = (t & 15) * 4, r0 = t >> 4;
    for (int it = 0; it < 4; ++it) {
        int r = r0 + it * 16;
        float4 v = *reinterpret_cast<const float4*>(&src[(size_t)(p0 + r) * WN + q0 + c4]);
        tile[r][c4 + 0] = f2b(v.x); tile[r][c4 + 1] = f2b(v.y);
        tile[r][c4 + 2] = f2b(v.z); tile[r][c4 + 3] = f2b(v.w);
    }
    __syncthreads();
    for (int it = 0; it < 4; ++it) {
        int q = r0 + it * 16;
        ushort4 o;
        o.x = tile[c4 + 0][q]; o.y = tile[c4 + 1][q];
        o.z = tile[c4 + 2][q]; o.w = tile[c4 + 3][q];
        *reinterpret_cast<ushort4*>(&dst[(size_t)(q0 + q) * WN + p0 + c4]) = o;
    }
}

// ---------------------------------------------------------------------------
// G1: per (b,i): a[(k*32+i)][m][q] = sum_p c1T[(k,m)][p] * xT[b,i][q][p]
//     r10 PASS version: A dbuf, vmcnt(2), XCD-grouped swizzle, row-major a.
// ---------------------------------------------------------------------------
__global__ __launch_bounds__(512, 4) void g1(const unsigned short* __restrict__ c1T,
                                             const unsigned short* __restrict__ xT,
                                             unsigned short* __restrict__ a, int b_base) {
    __shared__ unsigned short As[2][128 * 64];   // 32 KB
    __shared__ unsigned short Bs[256 * 64];      // 32 KB
    int p = blockIdx.x;
    int gpx = gridDim.x / 80;
    int xcd = p & 7, j = p >> 3;
    int grp = xcd * gpx + j / 10;           // bi group in [0, cur*32)
    int member = j % 10;                    // row-tile 0..9
    int bl = grp >> 5, i = grp & 31;
    int row0 = member * 128;                // (k,m) row base
    int b = b_base + bl;
    const unsigned short* Asrc = c1T;                              // pitch 256
    const unsigned short* Bsrc = xT + (size_t)(b * WC + i) * NN;   // [q][p], pitch 256
    unsigned short* Out = a + (size_t)bl * KC * NN;

    int t = threadIdx.x;
    int w = t >> 6, l = t & 63;
    int wm = (w >> 2) * 64, wn = (w & 3) * 64;
    int lr = l & 15, hi = l >> 4;
    int srow = l >> 3;                       // 0..7 within 8-row chunk
    int scol = ((l & 7) ^ srow) * 8;         // pre-swizzled source col (elems)

    f4 acc[4][4];
    for (int mf = 0; mf < 4; ++mf) for (int nf = 0; nf < 4; ++nf) acc[mf][nf] = (f4)(0.0f);

#define G1_STAGE_A(buf, step) do { \
    int p0_ = (step) * 64; \
    for (int it = 0; it < 2; ++it) { \
        int chunk = it * 8 + w; int row = chunk * 8 + srow; \
        gload16(&Asrc[(size_t)(row0 + row) * 256 + p0_ + scol], &As[buf][chunk * 512]); } \
} while (0)
#define G1_STAGE_B(step) do { \
    int p0_ = (step) * 64; \
    for (int it = 0; it < 4; ++it) { \
        int chunk = it * 8 + w; int row = chunk * 8 + srow; \
        gload16(&Bsrc[(size_t)row * 256 + p0_ + scol], &Bs[chunk * 512]); } \
} while (0)

    G1_STAGE_A(0, 0);                        // prologue: A(0) in flight
    for (int step = 0; step < 4; ++step) {
        int cur = step & 1;
        G1_STAGE_B(step);                    // B(t): 4 loads
        if (step < 3) {
            G1_STAGE_A(cur ^ 1, step + 1);   // A(t+1): 2 loads
            asm volatile("s_waitcnt vmcnt(2)" ::: "memory");
        } else {
            asm volatile("s_waitcnt vmcnt(0)" ::: "memory");
        }
        __builtin_amdgcn_s_barrier();        // tile t visible to all waves
        asm volatile("" ::: "memory");
        for (int kk = 0; kk < 2; ++kk) {
            bf8 af[4], bfr[4];
            for (int mf = 0; mf < 4; ++mf) {
                int r = wm + mf * 16 + lr;
                af[mf] = *(const bf8*)&As[cur][r * 64 + (((kk * 4 + hi) ^ (r & 7)) * 8)];
            }
            for (int nf = 0; nf < 4; ++nf) {
                int rb = wn + nf * 16 + lr;
                bfr[nf] = *(const bf8*)&Bs[rb * 64 + (((kk * 4 + hi) ^ (rb & 7)) * 8)];
            }
            for (int mf = 0; mf < 4; ++mf)
                for (int nf = 0; nf < 4; ++nf)
                    acc[mf][nf] = __builtin_amdgcn_mfma_f32_16x16x32_bf16(af[mf], bfr[nf], acc[mf][nf], 0, 0, 0);
        }
        asm volatile("" ::: "memory");
        __builtin_amdgcn_s_barrier();        // done reading Bs / As[cur]
    }
#undef G1_STAGE_A
#undef G1_STAGE_B
    for (int mf = 0; mf < 4; ++mf)
        for (int nf = 0; nf < 4; ++nf)
            for (int j2 = 0; j2 < 4; ++j2) {
                int grow = row0 + wm + mf * 16 + hi * 4 + j2;   // (k,m)
                int k = grow >> 8, m = grow & 255;
                int q = wn + nf * 16 + lr;
                Out[(size_t)(k * 32 + i) * NN + m * 256 + q] = f2b(acc[mf][nf][j2]);
            }
}

// ---------------------------------------------------------------------------
// G2P: c[(l,u)][(m,q)] = Wt @ a[ki][(m,q)]   (r6 PASS read-path)
//     Transpose-on-stage Bt[pix][ki] (pitch 172); vectorized ds_write_b64.
//     A-frags now from WtP: one coalesced 1KB wave-load per (kk,mf) from L2.
// ---------------------------------------------------------------------------
__global__ __launch_bounds__(512, 4) void g2p(const unsigned short* __restrict__ WtP,
                                              const unsigned short* __restrict__ a,
                                              unsigned short* __restrict__ c) {
    __shared__ unsigned short Bt[128 * 172];
    int bl = blockIdx.y;
    int n0 = blockIdx.x * 128;
    const unsigned short* asrc = a + (size_t)bl * KC * NN;
    unsigned short* Out = c + (size_t)bl * KC * NN;
    int t = threadIdx.x;

    // 640 tasks: oct in [0,16) (8-pix group), kq in [0,40) (4-ki group)
    for (int s = 0; s < 2; ++s) {
        int task = t + s * 512;
        if (task < 640) {
            int oct = task & 15, kq = task >> 4;
            const unsigned short* src = asrc + (size_t)(kq * 4) * NN + n0 + oct * 8;
            us8 v0 = *(const us8*)&src[0 * NN];
            us8 v1 = *(const us8*)&src[1 * NN];
            us8 v2 = *(const us8*)&src[2 * NN];
            us8 v3 = *(const us8*)&src[3 * NN];
            #pragma unroll
            for (int j = 0; j < 8; ++j) {
                ushort4 wv;
                wv.x = v0[j]; wv.y = v1[j]; wv.z = v2[j]; wv.w = v3[j];
                *reinterpret_cast<ushort4*>(&Bt[(oct * 8 + j) * 172 + kq * 4]) = wv;
            }
        }
    }
    __syncthreads();

    int w = t >> 6, l = t & 63;
    int mh = w >> 2, nq = w & 3;
    int lr = l & 15, hi = l >> 4;
    f4 acc[5][2];
    for (int mf = 0; mf < 5; ++mf) { acc[mf][0] = (f4)(0.0f); acc[mf][1] = (f4)(0.0f); }

    for (int kk = 0; kk < 5; ++kk) {
        int k0 = kk * 32 + hi * 8;
        bf8 bfr[2];
        #pragma unroll
        for (int nf = 0; nf < 2; ++nf) {
            int pix = (nq * 2 + nf) * 16 + lr;
            typedef __attribute__((ext_vector_type(4))) short s4v;
            s4v lo  = *(const s4v*)&Bt[pix * 172 + k0];
            s4v hi4 = *(const s4v*)&Bt[pix * 172 + k0 + 4];
            bfr[nf] = __builtin_shufflevector(lo, hi4, 0, 1, 2, 3, 4, 5, 6, 7);
        }
        #pragma unroll
        for (int mf = 0; mf < 5; ++mf) {
            // coalesced fragment load: lane l reads its own 16B
            bf8 afr = *(const bf8*)&WtP[(size_t)((((mh * 5 + kk) * 5 + mf) << 6) + l) * 8];
            acc[mf][0] = __builtin_amdgcn_mfma_f32_16x16x32_bf16(afr, bfr[0], acc[mf][0], 0, 0, 0);
            acc[mf][1] = __builtin_amdgcn_mfma_f32_16x16x32_bf16(afr, bfr[1], acc[mf][1], 0, 0, 0);
        }
    }
    for (int mf = 0; mf < 5; ++mf)
        for (int nf = 0; nf < 2; ++nf)
            for (int j = 0; j < 4; ++j) {
                int row = mh * 80 + mf * 16 + hi * 4 + j;       // (l,u)
                int col = n0 + (nq * 2 + nf) * 16 + lr;         // (m,q)
                Out[(size_t)row * NN + col] = f2b(acc[mf][nf][j]);
            }
}

// ---------------------------------------------------------------------------
// G3: out[b][u][m][n] = sum_{l,q} c[(l*32+u)][(m,q)] * c2T[n][(l,q)]
//     (r9 PASS version: A dbuf 2x16KB, B 32KB, vmcnt(2), ~62us)
// ---------------------------------------------------------------------------
__global__ __launch_bounds__(512, 4) void g3(const unsigned short* __restrict__ c,
                                             const unsigned short* __restrict__ c2T,
                                             float* __restrict__ out, int b_base) {
    __shared__ unsigned short As[2][128 * 64];     // 32 KB
    __shared__ unsigned short Bs[256 * 64];        // 32 KB
    int bl = blockIdx.y;
    int b = b_base + bl;
    int R0 = blockIdx.x * 128;             // (u,m); u fixed per block
    int u = R0 >> 8, m0 = R0 & 255;
    const unsigned short* Csrc = c + (size_t)bl * KC * NN;

    int t = threadIdx.x;
    int w = t >> 6, l = t & 63;
    int wm = (w >> 2) * 64, wn = (w & 3) * 64;
    int lr = l & 15, hi = l >> 4;
    int srow = l >> 3;
    int scol = ((l & 7) ^ srow) * 8;

    f4 acc[4][4];
    for (int mf = 0; mf < 4; ++mf) for (int nf = 0; nf < 4; ++nf) acc[mf][nf] = (f4)(0.0f);

#define G3_STAGE_A(buf, step) do { \
    int lq_ = (step) >> 2, q0_ = ((step) & 3) * 64; \
    const unsigned short* Arow0 = Csrc + (size_t)(lq_ * 32 + u) * NN + (size_t)m0 * 256 + q0_; \
    for (int it = 0; it < 2; ++it) { \
        int chunk = it * 8 + w; int row = chunk * 8 + srow; \
        gload16(&Arow0[(size_t)row * 256 + scol], &As[buf][chunk * 512]); } \
} while (0)
#define G3_STAGE_B(step) do { \
    const unsigned short* Brow0 = c2T + (step) * 64; \
    for (int it = 0; it < 4; ++it) { \
        int chunk = it * 8 + w; int row = chunk * 8 + srow; \
        gload16(&Brow0[(size_t)row * KQ + scol], &Bs[chunk * 512]); } \
} while (0)

    G3_STAGE_A(0, 0);                        // prologue: A(0) in flight
    for (int step = 0; step < 20; ++step) {
        int cur = step & 1;
        G3_STAGE_B(step);                    // B(t): 4 loads, L2-hot
        if (step < 19) {
            G3_STAGE_A(cur ^ 1, step + 1);   // A(t+1): 2 loads, one step early
            asm volatile("s_waitcnt vmcnt(2)" ::: "memory");
        } else {
            asm volatile("s_waitcnt vmcnt(0)" ::: "memory");
        }
        __builtin_amdgcn_s_barrier();        // tile t visible to all waves
        asm volatile("" ::: "memory");
        for (int kk = 0; kk < 2; ++kk) {
            bf8 af[4], bfr[4];
            for (int mf = 0; mf < 4; ++mf) {
                int r = wm + mf * 16 + lr;
                af[mf] = *(const bf8*)&As[cur][r * 64 + (((kk * 4 + hi) ^ (r & 7)) * 8)];
            }
            for (int nf = 0; nf < 4; ++nf) {
                int rb = wn + nf * 16 + lr;
                bfr[nf] = *(const bf8*)&Bs[rb * 64 + (((kk * 4 + hi) ^ (rb & 7)) * 8)];
            }
            for (int mf = 0; mf < 4; ++mf)
                for (int nf = 0; nf < 4; ++nf)
                    acc[mf][nf] = __builtin_amdgcn_mfma_f32_16x16x32_bf16(af[mf], bfr[nf], acc[mf][nf], 0, 0, 0);
        }
        asm volatile("" ::: "memory");
        __builtin_amdgcn_s_barrier();        // done reading Bs / As[cur]
    }
#undef G3_STAGE_A
#undef G3_STAGE_B
    for (int mf = 0; mf < 4; ++mf)
        for (int nf = 0; nf < 4; ++nf)
            for (int j = 0; j < 4; ++j) {
                int m = m0 + wm + mf * 16 + hi * 4 + j;
                int n = wn + nf * 16 + lr;
                out[((size_t)(b * WU + u) * WN + m) * WN + n] = acc[mf][nf][j];
            }
}

// ---------------------------------------------------------------------------
extern "C" void kernel_launch(void* const* d_in, const int* in_sizes, int n_in,
                              void* d_out, int out_size, void* d_ws, size_t ws_size,
                              hipStream_t stream) {
    const float* x     = (const float*)d_in[0];
    const float* cheb1 = (const float*)d_in[1];
    const float* cheb2 = (const float*)d_in[2];
    const float* coefs = (const float*)d_in[3];
    float* out = (float*)d_out;
    unsigned short* ws = (unsigned short*)d_ws;

    size_t off = 0;
    unsigned short* xT  = ws + off; off += (size_t)WB * WC * NN;
    unsigned short* c1T = ws + off; off += (size_t)WK * NN;
    unsigned short* c2T = ws + off; off += (size_t)WN * KQ;
    unsigned short* WtP = ws + off; off += (size_t)KC * KC;
    size_t fixed_elems = off;
    size_t a1 = (size_t)KC * NN;                 // one batch of a or c (elems)

    prep_small<<<1280, 256, 0, stream>>>(cheb1, cheb2, coefs, c1T, c2T, WtP);
    prep_x<<<dim3(4, 4, WB * WC), 256, 0, stream>>>(x, xT);

    size_t avail = ws_size / 2;
    size_t rem = avail > fixed_elems ? avail - fixed_elems : 0;

    if (rem >= 9 * a1) {
        // full-c path: chunk a by nb batches, single g3 over all 8
        int nb = (int)((rem - 8 * a1) / a1);
        if (nb < 1) nb = 1;
        if (nb > WB) nb = WB;
        unsigned short* a_ = ws + fixed_elems;
        unsigned short* c_ = a_ + (size_t)nb * a1;
        for (int b0 = 0; b0 < WB; b0 += nb) {
            int cur = (WB - b0 < nb) ? (WB - b0) : nb;
            g1<<<dim3(cur * 320), 512, 0, stream>>>(c1T, xT, a_, b0);
            g2p<<<dim3(512, cur), 512, 0, stream>>>(WtP, a_, c_ + (size_t)b0 * a1);
        }
        g3<<<dim3(64, WB), 512, 0, stream>>>(c_, c2T, out, 0);
    } else {
        // chunked fallback
        size_t per_b = 2 * a1;
        int nb = (int)(rem / per_b);
        if (nb < 1) nb = 1;
        if (nb > WB) nb = WB;
        unsigned short* a_ = ws + fixed_elems;
        unsigned short* c_ = a_ + (size_t)nb * a1;
        for (int b0 = 0; b0 < WB; b0 += nb) {
            int cur = (WB - b0 < nb) ? (WB - b0) : nb;
            g1<<<dim3(cur * 320), 512, 0, stream>>>(c1T, xT, a_, b0);
            g2p<<<dim3(512, cur), 512, 0, stream>>>(WtP, a_, c_);
            g3<<<dim3(64, cur), 512, 0, stream>>>(c_, c2T, out, b0);
        }
    }
}